// Round 1
// baseline (89.015 us; speedup 1.0000x reference)
//
#include <hip/hip_runtime.h>

#define B_N 4096
#define POOL_N 45
#define PACK_N 15
#define E_N 512
#define D_N 8
#define V_N 30000

// ws layout (floats):
//   wt  [512][24]  : transposed weights, col j: 0..7=q_w, 8..15=k_w, 16..23=v_w
//   tab [V][24]    : per-card projections, 0..7=q, 8..15=k(relu), 16..23=v(relu)
//   aux [B][32]    : 0..7 k_win, 8..15 v_win, 16..23 k_rank, 24..31 v_rank
#define WT_SZ  (E_N * 24)
#define TAB_SZ (V_N * 24)

// ---------------------------------------------------------------- K0: W^T ---
__global__ __launch_bounds__(256) void k_transpose_w(const float* __restrict__ q_w,
                                                     const float* __restrict__ k_w,
                                                     const float* __restrict__ v_w,
                                                     float* __restrict__ wt) {
  int i = blockIdx.x * 256 + threadIdx.x;  // [0, 512*24)
  if (i >= E_N * 24) return;
  int e = i / 24, j = i % 24;
  float val = (j < 8) ? q_w[j * E_N + e]
            : (j < 16) ? k_w[(j - 8) * E_N + e]
                       : v_w[(j - 16) * E_N + e];
  wt[i] = val;
}

// --------------------------------------------------- K1: projection table ---
// 2 waves per block: wave h=0 computes cols 0..11 (q0..7 raw, k0..3 relu),
// wave h=1 computes cols 12..23 (k4..7, v0..7, all relu). lane = table row.
// Weight addresses are wave-uniform -> s_load; emb streams per-lane (L1 x4 reuse).
__global__ __launch_bounds__(128) void k_build_tab(const float* __restrict__ emb,
                                                   const float* __restrict__ wt,
                                                   float* __restrict__ tab) {
  int lane = threadIdx.x & 63;
  int h = __builtin_amdgcn_readfirstlane(threadIdx.x >> 6);  // 0 or 1, uniform
  int r = blockIdx.x * 64 + lane;
  if (r >= V_N) return;
  const float* a = emb + (size_t)r * E_N;
  float acc[12];
#pragma unroll
  for (int j = 0; j < 12; ++j) acc[j] = 0.f;
  if (h == 0) {
    for (int e = 0; e < E_N; e += 4) {
      float4 av = *(const float4*)(a + e);
      float xs[4] = {av.x, av.y, av.z, av.w};
#pragma unroll
      for (int c = 0; c < 4; ++c) {
        float x = xs[c];
        float xr = fmaxf(x, 0.f);
        const float* wr = wt + (e + c) * 24;
#pragma unroll
        for (int j = 0; j < 8; ++j) acc[j] = fmaf(x, wr[j], acc[j]);
#pragma unroll
        for (int j = 8; j < 12; ++j) acc[j] = fmaf(xr, wr[j], acc[j]);
      }
    }
  } else {
    for (int e = 0; e < E_N; e += 4) {
      float4 av = *(const float4*)(a + e);
      float xs[4] = {av.x, av.y, av.z, av.w};
#pragma unroll
      for (int c = 0; c < 4; ++c) {
        float xr = fmaxf(xs[c], 0.f);
        const float* wr = wt + (e + c) * 24 + 12;
#pragma unroll
        for (int j = 0; j < 12; ++j) acc[j] = fmaf(xr, wr[j], acc[j]);
      }
    }
  }
  float* o = tab + (size_t)r * 24 + h * 12;
#pragma unroll
  for (int j = 0; j < 12; ++j) o[j] = acc[j];
}

// ------------------------------------------- K2: win/rank k,v rows per b ---
// grid (B/64, 2): blockIdx.y = which (0 win / 1 rank). Block (64,8): y = e-seg
// (wave-uniform -> weight s_load). LDS reduction over the 8 segs; no atomics.
__global__ __launch_bounds__(512) void k_build_aux(const float* __restrict__ wins,
                                                   const float* __restrict__ ranks,
                                                   const float* __restrict__ win_w,
                                                   const float* __restrict__ win_b,
                                                   const float* __restrict__ rank_w,
                                                   const float* __restrict__ rank_b,
                                                   const float* __restrict__ wt,
                                                   float* __restrict__ aux) {
  __shared__ float red[8][64][16];
  int lane = threadIdx.x;                                     // 0..63 = b-local
  int seg = __builtin_amdgcn_readfirstlane(threadIdx.y);      // 0..7, uniform
  int which = blockIdx.y;
  int b = blockIdx.x * 64 + lane;
  float s = which ? ranks[b] : wins[b];
  const float* ww = which ? rank_w : win_w;
  const float* wb = which ? rank_b : win_b;
  float acc[16];
#pragma unroll
  for (int j = 0; j < 16; ++j) acc[j] = 0.f;
  int e0 = seg * 64;
  for (int e = e0; e < e0 + 64; ++e) {
    float x = fmaf(s, ww[e], wb[e]);
    float xr = fmaxf(x, 0.f);
    const float* wr = wt + e * 24 + 8;  // k(8) + v(8) columns
#pragma unroll
    for (int j = 0; j < 16; ++j) acc[j] = fmaf(xr, wr[j], acc[j]);
  }
#pragma unroll
  for (int j = 0; j < 16; ++j) red[seg][lane][j] = acc[j];
  __syncthreads();
  int t = threadIdx.x + 64 * threadIdx.y;  // 0..511
#pragma unroll
  for (int rep = 0; rep < 2; ++rep) {
    int o = t + rep * 512;  // 0..1023 = 64 b x 16 j
    int bi = o >> 4, j = o & 15;
    float v = 0.f;
#pragma unroll
    for (int sgi = 0; sgi < 8; ++sgi) v += red[sgi][bi][j];
    aux[(size_t)(blockIdx.x * 64 + bi) * 32 + which * 16 + j] = v;
  }
}

// ----------------------------------------------------- K3: attention + out --
// 32-lane group per b (2 b per wave); lane = pack slot k (15 active).
__global__ __launch_bounds__(256) void k_main(const int* __restrict__ pool,
                                              const int* __restrict__ pack,
                                              const float* __restrict__ tab,
                                              const float* __restrict__ aux,
                                              const float* __restrict__ sc_w,
                                              const float* __restrict__ sc_b,
                                              float* __restrict__ out) {
  int grp = threadIdx.x >> 5;
  int lane = threadIdx.x & 31;
  int b = blockIdx.x * 8 + grp;
  int k = (lane < PACK_N) ? lane : 0;  // clamp idles to avoid OOB gathers
  int qidx = pack[(size_t)b * PACK_N + k];
  const float* qr = tab + (size_t)qidx * 24;
  float4 qa = *(const float4*)qr;
  float4 qb = *(const float4*)(qr + 4);
  const float rs = 0.35355339059327373f;  // 1/sqrt(8)
  const float* auxb = aux + (size_t)b * 32;
  float s[47];
  float m = 0.f;  // scores are relu'd -> max >= 0
#pragma unroll
  for (int p = 0; p < 47; ++p) {
    const float* kr;
    if (p < POOL_N) {
      int pi = pool[(size_t)b * POOL_N + p];
      kr = tab + (size_t)pi * 24 + 8;
    } else if (p == POOL_N) {
      kr = auxb;        // k_win
    } else {
      kr = auxb + 16;   // k_rank
    }
    float4 ka = *(const float4*)kr;
    float4 kb4 = *(const float4*)(kr + 4);
    float d = qa.x * ka.x;
    d = fmaf(qa.y, ka.y, d);
    d = fmaf(qa.z, ka.z, d);
    d = fmaf(qa.w, ka.w, d);
    d = fmaf(qb.x, kb4.x, d);
    d = fmaf(qb.y, kb4.y, d);
    d = fmaf(qb.z, kb4.z, d);
    d = fmaf(qb.w, kb4.w, d);
    d = fmaxf(d * rs, 0.f);
    s[p] = d;
    m = fmaxf(m, d);
  }
  float sum = 0.f;
#pragma unroll
  for (int p = 0; p < 47; ++p) {
    float e = __expf(s[p] - m);
    s[p] = e;
    sum += e;
  }
  float ctx[8] = {0.f, 0.f, 0.f, 0.f, 0.f, 0.f, 0.f, 0.f};
#pragma unroll
  for (int p = 0; p < 47; ++p) {
    const float* vr;
    if (p < POOL_N) {
      int pi = pool[(size_t)b * POOL_N + p];
      vr = tab + (size_t)pi * 24 + 16;
    } else if (p == POOL_N) {
      vr = auxb + 8;    // v_win
    } else {
      vr = auxb + 24;   // v_rank
    }
    float4 va = *(const float4*)vr;
    float4 vb4 = *(const float4*)(vr + 4);
    float w = s[p];
    ctx[0] = fmaf(w, va.x, ctx[0]);
    ctx[1] = fmaf(w, va.y, ctx[1]);
    ctx[2] = fmaf(w, va.z, ctx[2]);
    ctx[3] = fmaf(w, va.w, ctx[3]);
    ctx[4] = fmaf(w, vb4.x, ctx[4]);
    ctx[5] = fmaf(w, vb4.y, ctx[5]);
    ctx[6] = fmaf(w, vb4.z, ctx[6]);
    ctx[7] = fmaf(w, vb4.w, ctx[7]);
  }
  float inv = 1.f / sum;
  float logit = 0.f;
#pragma unroll
  for (int d0 = 0; d0 < 8; ++d0) {
    float c = ctx[d0] * inv;
    c = (c > 0.f) ? c : 0.01f * c;  // leaky_relu
    logit = fmaf(c, sc_w[d0], logit);
  }
  logit += sc_b[0];
  if (lane < PACK_N) out[(size_t)b * PACK_N + lane] = logit;
}

extern "C" void kernel_launch(void* const* d_in, const int* in_sizes, int n_in,
                              void* d_out, int out_size, void* d_ws, size_t ws_size,
                              hipStream_t stream) {
  const int* pool = (const int*)d_in[0];
  const int* pack = (const int*)d_in[1];
  const float* wins = (const float*)d_in[2];
  const float* ranks = (const float*)d_in[3];
  const float* emb = (const float*)d_in[4];
  const float* win_w = (const float*)d_in[5];
  const float* win_b = (const float*)d_in[6];
  const float* rank_w = (const float*)d_in[7];
  const float* rank_b = (const float*)d_in[8];
  const float* q_w = (const float*)d_in[9];
  const float* k_w = (const float*)d_in[10];
  const float* v_w = (const float*)d_in[11];
  const float* sc_w = (const float*)d_in[12];
  const float* sc_b = (const float*)d_in[13];

  float* ws = (float*)d_ws;
  float* wt = ws;
  float* tab = ws + WT_SZ;
  float* aux = ws + WT_SZ + TAB_SZ;
  float* out = (float*)d_out;

  hipLaunchKernelGGL(k_transpose_w, dim3(48), dim3(256), 0, stream,
                     q_w, k_w, v_w, wt);
  hipLaunchKernelGGL(k_build_tab, dim3((V_N + 63) / 64), dim3(128), 0, stream,
                     emb, wt, tab);
  hipLaunchKernelGGL(k_build_aux, dim3(B_N / 64, 2), dim3(64, 8), 0, stream,
                     wins, ranks, win_w, win_b, rank_w, rank_b, wt, aux);
  hipLaunchKernelGGL(k_main, dim3(B_N / 8), dim3(256), 0, stream,
                     pool, pack, tab, aux, sc_w, sc_b, out);
}

// Round 2
// 61.551 us; speedup vs baseline: 1.4462x; 1.4462x over previous
//
#include <hip/hip_runtime.h>

#define B_N 4096
#define POOL_N 45
#define PACK_N 15
#define E_N 512
#define D_N 8
#define V_N 30000

// ws layout (floats):
//   wt  [512][24]  : transposed weights, col j: 0..7=q_w, 8..15=k_w, 16..23=v_w
//   tab [V][24]    : per-card projections, 0..7=q, 8..15=k(relu), 16..23=v(relu)
//   aux [B][32]    : 0..7 k_win, 8..15 v_win, 16..23 k_rank, 24..31 v_rank
#define WT_SZ  (E_N * 24)
#define TAB_SZ (V_N * 24)

// ---------------------------------------------------------------- K0: W^T ---
__global__ __launch_bounds__(256) void k_transpose_w(const float* __restrict__ q_w,
                                                     const float* __restrict__ k_w,
                                                     const float* __restrict__ v_w,
                                                     float* __restrict__ wt) {
  int i = blockIdx.x * 256 + threadIdx.x;  // [0, 512*24)
  if (i >= E_N * 24) return;
  int e = i / 24, j = i % 24;
  float val = (j < 8) ? q_w[j * E_N + e]
            : (j < 16) ? k_w[(j - 8) * E_N + e]
                       : v_w[(j - 16) * E_N + e];
  wt[i] = val;
}

// --------------------------------------------------- K1: projection table ---
// 8 waves/block, 64 rows/block. Wave w handles e-slice [w*64, w*64+64) for all
// 24 columns (weight addr wave-uniform -> s_load broadcast); lane = row.
// LDS reduce over the 8 e-slices, then coalesced tab write.
__global__ __launch_bounds__(512) void k_build_tab(const float* __restrict__ emb,
                                                   const float* __restrict__ wt,
                                                   float* __restrict__ tab) {
  __shared__ float red[8][64][25];  // padded to kill bank conflicts
  int lane = threadIdx.x & 63;
  int w = __builtin_amdgcn_readfirstlane(threadIdx.x >> 6);  // 0..7, uniform
  int r = blockIdx.x * 64 + lane;
  float acc[24];
#pragma unroll
  for (int j = 0; j < 24; ++j) acc[j] = 0.f;
  if (r < V_N) {
    const float* a = emb + (size_t)r * E_N + w * 64;
    const float* wp = wt + (w * 64) * 24;
#pragma unroll 4
    for (int i = 0; i < 16; ++i) {  // 16 x float4 = 64 e-values
      float4 av = ((const float4*)a)[i];
      float xs[4] = {av.x, av.y, av.z, av.w};
#pragma unroll
      for (int c = 0; c < 4; ++c) {
        float x = xs[c];
        float xr = fmaxf(x, 0.f);
        const float* wr = wp + (i * 4 + c) * 24;
#pragma unroll
        for (int j = 0; j < 8; ++j) acc[j] = fmaf(x, wr[j], acc[j]);
#pragma unroll
        for (int j = 8; j < 24; ++j) acc[j] = fmaf(xr, wr[j], acc[j]);
      }
    }
  }
#pragma unroll
  for (int j = 0; j < 24; ++j) red[w][lane][j] = acc[j];
  __syncthreads();
  int t = threadIdx.x;
#pragma unroll
  for (int i = 0; i < 3; ++i) {
    int o = t + 512 * i;  // 0..1535 = 64 rows x 24 cols
    int row = o / 24, col = o - row * 24;
    int r_out = blockIdx.x * 64 + row;
    if (r_out < V_N) {
      float v = 0.f;
#pragma unroll
      for (int s = 0; s < 8; ++s) v += red[s][row][col];
      tab[(size_t)r_out * 24 + col] = v;
    }
  }
}

// ------------------------------------------- K2: win/rank k,v rows per b ---
__global__ __launch_bounds__(512) void k_build_aux(const float* __restrict__ wins,
                                                   const float* __restrict__ ranks,
                                                   const float* __restrict__ win_w,
                                                   const float* __restrict__ win_b,
                                                   const float* __restrict__ rank_w,
                                                   const float* __restrict__ rank_b,
                                                   const float* __restrict__ wt,
                                                   float* __restrict__ aux) {
  __shared__ float red[8][64][16];
  int lane = threadIdx.x;                                     // 0..63 = b-local
  int seg = __builtin_amdgcn_readfirstlane(threadIdx.y);      // 0..7, uniform
  int which = blockIdx.y;
  int b = blockIdx.x * 64 + lane;
  float s = which ? ranks[b] : wins[b];
  const float* ww = which ? rank_w : win_w;
  const float* wb = which ? rank_b : win_b;
  float acc[16];
#pragma unroll
  for (int j = 0; j < 16; ++j) acc[j] = 0.f;
  int e0 = seg * 64;
  for (int e = e0; e < e0 + 64; ++e) {
    float x = fmaf(s, ww[e], wb[e]);
    float xr = fmaxf(x, 0.f);
    const float* wr = wt + e * 24 + 8;  // k(8) + v(8) columns
#pragma unroll
    for (int j = 0; j < 16; ++j) acc[j] = fmaf(xr, wr[j], acc[j]);
  }
#pragma unroll
  for (int j = 0; j < 16; ++j) red[seg][lane][j] = acc[j];
  __syncthreads();
  int t = threadIdx.x + 64 * threadIdx.y;  // 0..511
#pragma unroll
  for (int rep = 0; rep < 2; ++rep) {
    int o = t + rep * 512;  // 0..1023 = 64 b x 16 j
    int bi = o >> 4, j = o & 15;
    float v = 0.f;
#pragma unroll
    for (int sgi = 0; sgi < 8; ++sgi) v += red[sgi][bi][j];
    aux[(size_t)(blockIdx.x * 64 + bi) * 32 + which * 16 + j] = v;
  }
}

// ----------------------------------------------------- K3: attention + out --
// 32-lane group per b (2 b per wave); lane = pack slot k (15 active).
__global__ __launch_bounds__(256) void k_main(const int* __restrict__ pool,
                                              const int* __restrict__ pack,
                                              const float* __restrict__ tab,
                                              const float* __restrict__ aux,
                                              const float* __restrict__ sc_w,
                                              const float* __restrict__ sc_b,
                                              float* __restrict__ out) {
  int grp = threadIdx.x >> 5;
  int lane = threadIdx.x & 31;
  int b = blockIdx.x * 8 + grp;
  int k = (lane < PACK_N) ? lane : 0;  // clamp idles to avoid OOB gathers
  int qidx = pack[(size_t)b * PACK_N + k];
  const float* qr = tab + (size_t)qidx * 24;
  float4 qa = *(const float4*)qr;
  float4 qb = *(const float4*)(qr + 4);
  const float rs = 0.35355339059327373f;  // 1/sqrt(8)
  const float* auxb = aux + (size_t)b * 32;
  float s[47];
  float m = 0.f;  // scores are relu'd -> max >= 0
#pragma unroll
  for (int p = 0; p < 47; ++p) {
    const float* kr;
    if (p < POOL_N) {
      int pi = pool[(size_t)b * POOL_N + p];
      kr = tab + (size_t)pi * 24 + 8;
    } else if (p == POOL_N) {
      kr = auxb;        // k_win
    } else {
      kr = auxb + 16;   // k_rank
    }
    float4 ka = *(const float4*)kr;
    float4 kb4 = *(const float4*)(kr + 4);
    float d = qa.x * ka.x;
    d = fmaf(qa.y, ka.y, d);
    d = fmaf(qa.z, ka.z, d);
    d = fmaf(qa.w, ka.w, d);
    d = fmaf(qb.x, kb4.x, d);
    d = fmaf(qb.y, kb4.y, d);
    d = fmaf(qb.z, kb4.z, d);
    d = fmaf(qb.w, kb4.w, d);
    d = fmaxf(d * rs, 0.f);
    s[p] = d;
    m = fmaxf(m, d);
  }
  float sum = 0.f;
#pragma unroll
  for (int p = 0; p < 47; ++p) {
    float e = __expf(s[p] - m);
    s[p] = e;
    sum += e;
  }
  float ctx[8] = {0.f, 0.f, 0.f, 0.f, 0.f, 0.f, 0.f, 0.f};
#pragma unroll
  for (int p = 0; p < 47; ++p) {
    const float* vr;
    if (p < POOL_N) {
      int pi = pool[(size_t)b * POOL_N + p];
      vr = tab + (size_t)pi * 24 + 16;
    } else if (p == POOL_N) {
      vr = auxb + 8;    // v_win
    } else {
      vr = auxb + 24;   // v_rank
    }
    float4 va = *(const float4*)vr;
    float4 vb4 = *(const float4*)(vr + 4);
    float w = s[p];
    ctx[0] = fmaf(w, va.x, ctx[0]);
    ctx[1] = fmaf(w, va.y, ctx[1]);
    ctx[2] = fmaf(w, va.z, ctx[2]);
    ctx[3] = fmaf(w, va.w, ctx[3]);
    ctx[4] = fmaf(w, vb4.x, ctx[4]);
    ctx[5] = fmaf(w, vb4.y, ctx[5]);
    ctx[6] = fmaf(w, vb4.z, ctx[6]);
    ctx[7] = fmaf(w, vb4.w, ctx[7]);
  }
  float inv = 1.f / sum;
  float logit = 0.f;
#pragma unroll
  for (int d0 = 0; d0 < 8; ++d0) {
    float c = ctx[d0] * inv;
    c = (c > 0.f) ? c : 0.01f * c;  // leaky_relu
    logit = fmaf(c, sc_w[d0], logit);
  }
  logit += sc_b[0];
  if (lane < PACK_N) out[(size_t)b * PACK_N + lane] = logit;
}

extern "C" void kernel_launch(void* const* d_in, const int* in_sizes, int n_in,
                              void* d_out, int out_size, void* d_ws, size_t ws_size,
                              hipStream_t stream) {
  const int* pool = (const int*)d_in[0];
  const int* pack = (const int*)d_in[1];
  const float* wins = (const float*)d_in[2];
  const float* ranks = (const float*)d_in[3];
  const float* emb = (const float*)d_in[4];
  const float* win_w = (const float*)d_in[5];
  const float* win_b = (const float*)d_in[6];
  const float* rank_w = (const float*)d_in[7];
  const float* rank_b = (const float*)d_in[8];
  const float* q_w = (const float*)d_in[9];
  const float* k_w = (const float*)d_in[10];
  const float* v_w = (const float*)d_in[11];
  const float* sc_w = (const float*)d_in[12];
  const float* sc_b = (const float*)d_in[13];

  float* ws = (float*)d_ws;
  float* wt = ws;
  float* tab = ws + WT_SZ;
  float* aux = ws + WT_SZ + TAB_SZ;
  float* out = (float*)d_out;

  hipLaunchKernelGGL(k_transpose_w, dim3(48), dim3(256), 0, stream,
                     q_w, k_w, v_w, wt);
  hipLaunchKernelGGL(k_build_tab, dim3((V_N + 63) / 64), dim3(512), 0, stream,
                     emb, wt, tab);
  hipLaunchKernelGGL(k_build_aux, dim3(B_N / 64, 2), dim3(64, 8), 0, stream,
                     wins, ranks, win_w, win_b, rank_w, rank_b, wt, aux);
  hipLaunchKernelGGL(k_main, dim3(B_N / 8), dim3(256), 0, stream,
                     pool, pack, tab, aux, sc_w, sc_b, out);
}

// Round 3
// 53.834 us; speedup vs baseline: 1.6535x; 1.1434x over previous
//
#include <hip/hip_runtime.h>

#define B_N 4096
#define POOL_N 45
#define PACK_N 15
#define E_N 512
#define D_N 8
#define V_N 30000

// ws layout (floats):
//   wt  [512][24]  : transposed weights, col j: 0..7=q_w, 8..15=k_w, 16..23=v_w
//   tab [V][24]    : per-card projections, 0..7=q, 8..15=k(relu), 16..23=v(relu)
//   aux [B][32]    : 0..7 k_win, 8..15 v_win, 16..23 k_rank, 24..31 v_rank
#define WT_SZ  (E_N * 24)
#define TAB_SZ (V_N * 24)

// ---------------------------------------------------------------- K0: W^T ---
__global__ __launch_bounds__(256) void k_transpose_w(const float* __restrict__ q_w,
                                                     const float* __restrict__ k_w,
                                                     const float* __restrict__ v_w,
                                                     float* __restrict__ wt) {
  int i = blockIdx.x * 256 + threadIdx.x;  // [0, 512*24)
  if (i >= E_N * 24) return;
  int e = i / 24, j = i % 24;
  float val = (j < 8) ? q_w[j * E_N + e]
            : (j < 16) ? k_w[(j - 8) * E_N + e]
                       : v_w[(j - 16) * E_N + e];
  wt[i] = val;
}

// --------------------------------------------------- K1: projection table ---
// 8 waves/block, 64 rows/block. Wave w handles e-slice [w*64, w*64+64) for all
// 24 columns (weight addr wave-uniform -> s_load broadcast); lane = row.
// LDS reduce over the 8 e-slices, then coalesced tab write.
__global__ __launch_bounds__(512) void k_build_tab(const float* __restrict__ emb,
                                                   const float* __restrict__ wt,
                                                   float* __restrict__ tab) {
  __shared__ float red[8][64][25];  // padded to kill bank conflicts
  int lane = threadIdx.x & 63;
  int w = __builtin_amdgcn_readfirstlane(threadIdx.x >> 6);  // 0..7, uniform
  int r = blockIdx.x * 64 + lane;
  float acc[24];
#pragma unroll
  for (int j = 0; j < 24; ++j) acc[j] = 0.f;
  if (r < V_N) {
    const float* a = emb + (size_t)r * E_N + w * 64;
    const float* wp = wt + (w * 64) * 24;
#pragma unroll 4
    for (int i = 0; i < 16; ++i) {  // 16 x float4 = 64 e-values
      float4 av = ((const float4*)a)[i];
      float xs[4] = {av.x, av.y, av.z, av.w};
#pragma unroll
      for (int c = 0; c < 4; ++c) {
        float x = xs[c];
        float xr = fmaxf(x, 0.f);
        const float* wr = wp + (i * 4 + c) * 24;
#pragma unroll
        for (int j = 0; j < 8; ++j) acc[j] = fmaf(x, wr[j], acc[j]);
#pragma unroll
        for (int j = 8; j < 24; ++j) acc[j] = fmaf(xr, wr[j], acc[j]);
      }
    }
  }
#pragma unroll
  for (int j = 0; j < 24; ++j) red[w][lane][j] = acc[j];
  __syncthreads();
  int t = threadIdx.x;
#pragma unroll
  for (int i = 0; i < 3; ++i) {
    int o = t + 512 * i;  // 0..1535 = 64 rows x 24 cols
    int row = o / 24, col = o - row * 24;
    int r_out = blockIdx.x * 64 + row;
    if (r_out < V_N) {
      float v = 0.f;
#pragma unroll
      for (int s = 0; s < 8; ++s) v += red[s][row][col];
      tab[(size_t)r_out * 24 + col] = v;
    }
  }
}

// ------------------------------------------- K2: win/rank k,v rows per b ---
// grid (B/16, 2): 512 blocks (2/CU). Block 256: thread = (seg 0..15, b-local
// 0..15); each thread covers 32 e-values; LDS reduce over 16 segs.
__global__ __launch_bounds__(256) void k_build_aux(const float* __restrict__ wins,
                                                   const float* __restrict__ ranks,
                                                   const float* __restrict__ win_w,
                                                   const float* __restrict__ win_b,
                                                   const float* __restrict__ rank_w,
                                                   const float* __restrict__ rank_b,
                                                   const float* __restrict__ wt,
                                                   float* __restrict__ aux) {
  __shared__ float red[16][16][17];
  int t = threadIdx.x;
  int bl = t & 15, seg = t >> 4;
  int which = blockIdx.y;
  int b = blockIdx.x * 16 + bl;
  float s = which ? ranks[b] : wins[b];
  const float* ww = which ? rank_w : win_w;
  const float* wb = which ? rank_b : win_b;
  float acc[16];
#pragma unroll
  for (int j = 0; j < 16; ++j) acc[j] = 0.f;
  int e0 = seg * 32;
#pragma unroll 4
  for (int e = e0; e < e0 + 32; ++e) {
    float x = fmaf(s, ww[e], wb[e]);
    float xr = fmaxf(x, 0.f);
    const float* wr = wt + e * 24 + 8;  // k(8) + v(8) columns
#pragma unroll
    for (int j = 0; j < 16; ++j) acc[j] = fmaf(xr, wr[j], acc[j]);
  }
#pragma unroll
  for (int j = 0; j < 16; ++j) red[seg][bl][j] = acc[j];
  __syncthreads();
  int bi = t >> 4, j = t & 15;
  float v = 0.f;
#pragma unroll
  for (int sg = 0; sg < 16; ++sg) v += red[sg][bi][j];
  aux[(size_t)(blockIdx.x * 16 + bi) * 32 + which * 16 + j] = v;
}

// ----------------------------------------------------- K3: attention + out --
// 32-lane group per b; lane = pack slot k. Single pass, online softmax.
// Pool indices prefetched into 2 regs/lane, broadcast via __shfl (kills the
// idx-load -> row-load dependent chain). K|V are 16 contiguous floats per row.
__global__ __launch_bounds__(256) void k_main(const int* __restrict__ pool,
                                              const int* __restrict__ pack,
                                              const float* __restrict__ tab,
                                              const float* __restrict__ aux,
                                              const float* __restrict__ sc_w,
                                              const float* __restrict__ sc_b,
                                              float* __restrict__ out) {
  int grp = threadIdx.x >> 5;
  int lane = threadIdx.x & 31;
  int b = blockIdx.x * 8 + grp;
  // prefetch pool indices: lane l holds p=l and p=32+l
  int i0 = pool[(size_t)b * POOL_N + lane];
  int i1 = (lane < POOL_N - 32) ? pool[(size_t)b * POOL_N + 32 + lane] : 0;
  int k = (lane < PACK_N) ? lane : 0;  // clamp idles to avoid OOB gathers
  int qidx = pack[(size_t)b * PACK_N + k];
  const float* qr = tab + (size_t)qidx * 24;
  float4 qa = *(const float4*)qr;
  float4 qb = *(const float4*)(qr + 4);
  const float rs = 0.35355339059327373f;  // 1/sqrt(8)
  const float* auxb = aux + (size_t)b * 32;

  float m = 0.f, sum = 0.f;  // scores relu'd -> max >= 0
  float ctx[8] = {0.f, 0.f, 0.f, 0.f, 0.f, 0.f, 0.f, 0.f};

  auto att_step = [&](const float* kr) {
    float4 k0 = *(const float4*)kr;
    float4 k1 = *(const float4*)(kr + 4);
    float4 v0 = *(const float4*)(kr + 8);
    float4 v1 = *(const float4*)(kr + 12);
    float d = qa.x * k0.x;
    d = fmaf(qa.y, k0.y, d);
    d = fmaf(qa.z, k0.z, d);
    d = fmaf(qa.w, k0.w, d);
    d = fmaf(qb.x, k1.x, d);
    d = fmaf(qb.y, k1.y, d);
    d = fmaf(qb.z, k1.z, d);
    d = fmaf(qb.w, k1.w, d);
    d = fmaxf(d * rs, 0.f);
    // one transcendental per step: t = exp(-|d-m|) serves as either the
    // rescale (d>m) or the new term (d<=m); the other factor is exactly 1.
    float t = __expf(-fabsf(d - m));
    bool up = d > m;
    float sc = up ? t : 1.f;
    float e = up ? 1.f : t;
    m = fmaxf(m, d);
    sum = fmaf(sum, sc, e);
    ctx[0] = fmaf(ctx[0], sc, e * v0.x);
    ctx[1] = fmaf(ctx[1], sc, e * v0.y);
    ctx[2] = fmaf(ctx[2], sc, e * v0.z);
    ctx[3] = fmaf(ctx[3], sc, e * v0.w);
    ctx[4] = fmaf(ctx[4], sc, e * v1.x);
    ctx[5] = fmaf(ctx[5], sc, e * v1.y);
    ctx[6] = fmaf(ctx[6], sc, e * v1.z);
    ctx[7] = fmaf(ctx[7], sc, e * v1.w);
  };

#pragma unroll 8
  for (int p = 0; p < 32; ++p) {
    int pi = __shfl(i0, p, 32);
    att_step(tab + (size_t)pi * 24 + 8);
  }
#pragma unroll
  for (int p = 0; p < 13; ++p) {
    int pi = __shfl(i1, p, 32);
    att_step(tab + (size_t)pi * 24 + 8);
  }
  att_step(auxb);        // win  (k at +0, v at +8)
  att_step(auxb + 16);   // rank

  float inv = 1.f / sum;
  float logit = 0.f;
#pragma unroll
  for (int d0 = 0; d0 < 8; ++d0) {
    float c = ctx[d0] * inv;
    c = (c > 0.f) ? c : 0.01f * c;  // leaky_relu
    logit = fmaf(c, sc_w[d0], logit);
  }
  logit += sc_b[0];
  if (lane < PACK_N) out[(size_t)b * PACK_N + lane] = logit;
}

extern "C" void kernel_launch(void* const* d_in, const int* in_sizes, int n_in,
                              void* d_out, int out_size, void* d_ws, size_t ws_size,
                              hipStream_t stream) {
  const int* pool = (const int*)d_in[0];
  const int* pack = (const int*)d_in[1];
  const float* wins = (const float*)d_in[2];
  const float* ranks = (const float*)d_in[3];
  const float* emb = (const float*)d_in[4];
  const float* win_w = (const float*)d_in[5];
  const float* win_b = (const float*)d_in[6];
  const float* rank_w = (const float*)d_in[7];
  const float* rank_b = (const float*)d_in[8];
  const float* q_w = (const float*)d_in[9];
  const float* k_w = (const float*)d_in[10];
  const float* v_w = (const float*)d_in[11];
  const float* sc_w = (const float*)d_in[12];
  const float* sc_b = (const float*)d_in[13];

  float* ws = (float*)d_ws;
  float* wt = ws;
  float* tab = ws + WT_SZ;
  float* aux = ws + WT_SZ + TAB_SZ;
  float* out = (float*)d_out;

  hipLaunchKernelGGL(k_transpose_w, dim3(48), dim3(256), 0, stream,
                     q_w, k_w, v_w, wt);
  hipLaunchKernelGGL(k_build_tab, dim3((V_N + 63) / 64), dim3(512), 0, stream,
                     emb, wt, tab);
  hipLaunchKernelGGL(k_build_aux, dim3(B_N / 16, 2), dim3(256), 0, stream,
                     wins, ranks, win_w, win_b, rank_w, rank_b, wt, aux);
  hipLaunchKernelGGL(k_main, dim3(B_N / 8), dim3(256), 0, stream,
                     pool, pack, tab, aux, sc_w, sc_b, out);
}